// Round 2
// baseline (415.709 us; speedup 1.0000x reference)
//
#include <hip/hip_runtime.h>

typedef float f32x4 __attribute__((ext_vector_type(4)));
typedef float f32x16 __attribute__((ext_vector_type(16)));
typedef short s16x8 __attribute__((ext_vector_type(8)));
typedef unsigned int u32x4 __attribute__((ext_vector_type(4)));

#define B_SZ 4
#define T_SZ 2048
#define D_SZ 1024
#define NH 16
#define HD 64

// ---------- helpers ----------
__device__ __forceinline__ unsigned short f2b(float f) {
  unsigned int u = __builtin_bit_cast(unsigned int, f);
  unsigned int r = (u + 0x7fffu + ((u >> 16) & 1u)) >> 16;  // RNE
  return (unsigned short)r;
}

__device__ __forceinline__ void gld_lds16(void* lds, const void* g) {
  __builtin_amdgcn_global_load_lds(
      (const __attribute__((address_space(1))) unsigned int*)g,
      (__attribute__((address_space(3))) unsigned int*)lds, 16, 0, 0);
}

// ---------- fp32 -> bf16 cast ----------
__global__ void cast_kernel(const float* __restrict__ in,
                            unsigned short* __restrict__ out, int n4) {
  int i = blockIdx.x * blockDim.x + threadIdx.x;
  if (i < n4) {
    float4 v = reinterpret_cast<const float4*>(in)[i];
    ushort4 o;
    o.x = f2b(v.x); o.y = f2b(v.y); o.z = f2b(v.z); o.w = f2b(v.w);
    reinterpret_cast<ushort4*>(out)[i] = o;
  }
}

// ---------- GEMM: C[M,N] = A[M,K] * W[N,K]^T  (m97-style 128x128 tile) ----------
// MODE 0: bf16 out row-major [M,N].  MODE 1: f32 out row-major.
// MODE 2: bf16 out transposed per (b,h): Vt[(b*1024 + col)*2048 + t]
#define BM 128
#define BN 128
#define BKG 32

template <int MODE>
__global__ __launch_bounds__(256, 2) void gemm_bt(
    const unsigned short* __restrict__ A,
    const unsigned short* __restrict__ W,
    void* __restrict__ Cv, int M, int N, int K) {
  __shared__ __align__(16) unsigned short As[BM * BKG];
  __shared__ __align__(16) unsigned short Ws[BN * BKG];
  const int tid = threadIdx.x, wid = tid >> 6, lane = tid & 63;
  const int row0 = blockIdx.x * BM, col0 = blockIdx.y * BN;
  const int wr = (wid >> 1) * 64, wc = (wid & 1) * 64;
  const int fr = lane & 15, kg = (lane >> 4) * 8;
  f32x4 acc[4][4] = {};

  const int srow = lane >> 2;
  const int scol = (lane & 3) * 8;

  for (int k0 = 0; k0 < K; k0 += BKG) {
    __syncthreads();
#pragma unroll
    for (int i = 0; i < 2; ++i) {
      const int c = wid + 4 * i;
      gld_lds16(&As[c * 512], &A[(row0 + c * 16 + srow) * K + k0 + scol]);
      gld_lds16(&Ws[c * 512], &W[(col0 + c * 16 + srow) * K + k0 + scol]);
    }
    __syncthreads();
    s16x8 af[4], bf[4];
#pragma unroll
    for (int m = 0; m < 4; ++m)
      af[m] = *(const s16x8*)&As[(wr + m * 16 + fr) * BKG + kg];
#pragma unroll
    for (int n = 0; n < 4; ++n)
      bf[n] = *(const s16x8*)&Ws[(wc + n * 16 + fr) * BKG + kg];
#pragma unroll
    for (int m = 0; m < 4; ++m)
#pragma unroll
      for (int n = 0; n < 4; ++n)
        acc[m][n] = __builtin_amdgcn_mfma_f32_16x16x32_bf16(af[m], bf[n], acc[m][n], 0, 0, 0);
  }

  const int crow = row0 + wr + ((lane >> 4) << 2);
  const int ccol = col0 + wc + fr;
#pragma unroll
  for (int m = 0; m < 4; ++m)
#pragma unroll
    for (int n = 0; n < 4; ++n) {
      if constexpr (MODE == 2) {
        unsigned short* C = (unsigned short*)Cv;
        ushort4 pk;
        pk.x = f2b(acc[m][n][0]); pk.y = f2b(acc[m][n][1]);
        pk.z = f2b(acc[m][n][2]); pk.w = f2b(acc[m][n][3]);
        const int tok = crow + m * 16;
        const int c = ccol + n * 16;
        *(ushort4*)&C[((tok >> 11) * 1024 + c) * 2048 + (tok & 2047)] = pk;
      } else {
#pragma unroll
        for (int r = 0; r < 4; ++r) {
          const float v = acc[m][n][r];
          const int idx = (crow + m * 16 + r) * N + ccol + n * 16;
          if constexpr (MODE == 0)
            ((unsigned short*)Cv)[idx] = f2b(v);
          else
            ((float*)Cv)[idx] = v;
        }
      }
    }
}

// ---------- flash attention, swapped-operand, LDS-free ----------
// block = 4 waves x 32 q rows = 128 q; grid (T/128=16, B*NH=64), XCD-swizzled.
// Per wave: S^T = mfma32x32x16(K, Q) -> lane owns q=lane&31 column.
// Softmax fully lane-local (+1 shfl_xor(32)); P repacked via cvt_pk+permlane32.
// O^T = mfma(V^T, P^T); V^T read from the pre-transposed Vt produced by gemm MODE 2.
__global__ __launch_bounds__(256, 2) void attn_kernel(
    const unsigned short* __restrict__ Q,
    const unsigned short* __restrict__ K,
    const unsigned short* __restrict__ Vt,
    unsigned short* __restrict__ O) {
  const int tid = threadIdx.x, wid = tid >> 6, lane = tid & 63;
  const int ql = lane & 31;   // q column / kv-row-in-32-block
  const int hi = lane >> 5;

  // bijective XCD swizzle: 1024 blocks = 8 XCD * 128; same-bh q-chunks stay on one XCD
  const int lin = blockIdx.y * gridDim.x + blockIdx.x;
  const int work = (lin & 7) * 128 + (lin >> 3);
  const int qc = work & 15, bh = work >> 4;
  const int b = bh >> 4, h = bh & 15;
  const int q0 = qc * 128 + wid * 32;
  const int qkbase = b * T_SZ * D_SZ + h * HD;        // Q,K,O base
  const int vtbase = (b * D_SZ + h * HD) * T_SZ;      // Vt base

  // Q B-fragments (col = lane&31 = own q row, k = d)
  s16x8 qf[4];
#pragma unroll
  for (int kq = 0; kq < 4; ++kq)
    qf[kq] = *(const s16x8*)&Q[qkbase + (q0 + ql) * D_SZ + kq * 16 + hi * 8];

  f32x16 ot[2] = {};          // O^T accum: lane q=ql, d = dblk*32 + crow(r,hi)
  float m = -3e38f, l = 0.f;
  const float cl = 0.125f * 1.44269504089f;  // hd^-0.5 * log2(e)

  for (int kv0 = 0; kv0 < T_SZ; kv0 += 64) {
    // S^T = K * Q^T : rows kv, cols q
    f32x16 st[2] = {};
#pragma unroll
    for (int blk = 0; blk < 2; ++blk) {
      const int krow = qkbase + (kv0 + blk * 32 + ql) * D_SZ;
#pragma unroll
      for (int kq = 0; kq < 4; ++kq) {
        const s16x8 kf = *(const s16x8*)&K[krow + kq * 16 + hi * 8];
        st[blk] = __builtin_amdgcn_mfma_f32_32x32x16_bf16(kf, qf[kq], st[blk], 0, 0, 0);
      }
    }

    // issue V loads early: latency hides under softmax VALU chain
    s16x8 vf[4][2];
#pragma unroll
    for (int ks = 0; ks < 4; ++ks)
#pragma unroll
      for (int dblk = 0; dblk < 2; ++dblk)
        vf[ks][dblk] = *(const s16x8*)&Vt[vtbase + (dblk * 32 + ql) * T_SZ +
                                          kv0 + ks * 16 + hi * 8];

    // online softmax: lane owns one q column; 32 of 64 kv here, rest on lane^32
    float mx = st[0][0];
#pragma unroll
    for (int blk = 0; blk < 2; ++blk)
#pragma unroll
      for (int r = 0; r < 16; ++r) mx = fmaxf(mx, st[blk][r]);
    mx = fmaxf(mx, __shfl_xor(mx, 32, 64));
    const float mn = fmaxf(m, mx);
    const float alpha = __builtin_amdgcn_exp2f((m - mn) * cl);
    m = mn;
    float sum = 0.f;
#pragma unroll
    for (int blk = 0; blk < 2; ++blk)
#pragma unroll
      for (int r = 0; r < 16; ++r) {
        const float e = __builtin_amdgcn_exp2f((st[blk][r] - mn) * cl);
        st[blk][r] = e;  // reuse st as P storage
        sum += e;
      }
    sum += __shfl_xor(sum, 32, 64);
    l = l * alpha + sum;
#pragma unroll
    for (int dblk = 0; dblk < 2; ++dblk)
#pragma unroll
      for (int r = 0; r < 16; ++r) ot[dblk][r] *= alpha;

    // PV: O^T += V^T * P^T ; P^T B-fragments via cvt_pk + permlane32_swap
#pragma unroll
    for (int ks = 0; ks < 4; ++ks) {
      const int blk = ks >> 1, rb = (ks & 1) * 8;
      unsigned int a0, a1, b0, b1;
      asm("v_cvt_pk_bf16_f32 %0, %1, %2" : "=v"(a0) : "v"(st[blk][rb + 0]), "v"(st[blk][rb + 1]));
      asm("v_cvt_pk_bf16_f32 %0, %1, %2" : "=v"(a1) : "v"(st[blk][rb + 2]), "v"(st[blk][rb + 3]));
      asm("v_cvt_pk_bf16_f32 %0, %1, %2" : "=v"(b0) : "v"(st[blk][rb + 4]), "v"(st[blk][rb + 5]));
      asm("v_cvt_pk_bf16_f32 %0, %1, %2" : "=v"(b1) : "v"(st[blk][rb + 6]), "v"(st[blk][rb + 7]));
      asm("v_permlane32_swap_b32 %0, %1" : "+v"(a0), "+v"(b0));
      asm("v_permlane32_swap_b32 %0, %1" : "+v"(a1), "+v"(b1));
      u32x4 w = {a0, a1, b0, b1};  // elems kv = ks*16 + hi*8 + 0..7
      const s16x8 pf = __builtin_bit_cast(s16x8, w);
#pragma unroll
      for (int dblk = 0; dblk < 2; ++dblk)
        ot[dblk] = __builtin_amdgcn_mfma_f32_32x32x16_bf16(vf[ks][dblk], pf, ot[dblk], 0, 0, 0);
    }
  }

  // epilogue: normalize (lane-local l) and store bf16 rows of O[q][d]
  const float inv = 1.f / l;
  const int orow = qkbase + (q0 + ql) * D_SZ;
#pragma unroll
  for (int dblk = 0; dblk < 2; ++dblk)
#pragma unroll
    for (int qd = 0; qd < 4; ++qd) {  // d = dblk*32 + qd*8 + hi*4 + (0..3)
      ushort4 pk;
      pk.x = f2b(ot[dblk][qd * 4 + 0] * inv);
      pk.y = f2b(ot[dblk][qd * 4 + 1] * inv);
      pk.z = f2b(ot[dblk][qd * 4 + 2] * inv);
      pk.w = f2b(ot[dblk][qd * 4 + 3] * inv);
      *(ushort4*)&O[orow + dblk * 32 + qd * 8 + hi * 4] = pk;
    }
}

// ---------- launch ----------
extern "C" void kernel_launch(void* const* d_in, const int* in_sizes, int n_in,
                              void* d_out, int out_size, void* d_ws, size_t ws_size,
                              hipStream_t stream) {
  const float* x  = (const float*)d_in[0];
  const float* Wq = (const float*)d_in[1];
  const float* Wk = (const float*)d_in[2];
  const float* Wv = (const float*)d_in[3];
  const float* Wo = (const float*)d_in[4];

  const int NTOK = B_SZ * T_SZ;
  const int SZX = NTOK * D_SZ;
  const int SZW = D_SZ * D_SZ;

  unsigned short* ws  = (unsigned short*)d_ws;
  unsigned short* xb  = ws;             // x bf16; reused as attention output O
  unsigned short* wqb = xb + SZX;
  unsigned short* wkb = wqb + SZW;
  unsigned short* wvb = wkb + SZW;
  unsigned short* wob = wvb + SZW;
  unsigned short* Qb  = wob + SZW;
  unsigned short* Kb  = Qb + SZX;
  unsigned short* Vtb = Kb + SZX;       // V transposed per (b,h): [b*1024+c][t]

  cast_kernel<<<SZX / 1024, 256, 0, stream>>>(x, xb, SZX / 4);
  cast_kernel<<<SZW / 1024, 256, 0, stream>>>(Wq, wqb, SZW / 4);
  cast_kernel<<<SZW / 1024, 256, 0, stream>>>(Wk, wkb, SZW / 4);
  cast_kernel<<<SZW / 1024, 256, 0, stream>>>(Wv, wvb, SZW / 4);
  cast_kernel<<<SZW / 1024, 256, 0, stream>>>(Wo, wob, SZW / 4);

  dim3 gg(NTOK / BM, D_SZ / BN);
  gemm_bt<0><<<gg, 256, 0, stream>>>(xb, wqb, Qb, NTOK, D_SZ, D_SZ);
  gemm_bt<0><<<gg, 256, 0, stream>>>(xb, wkb, Kb, NTOK, D_SZ, D_SZ);
  gemm_bt<2><<<gg, 256, 0, stream>>>(xb, wvb, Vtb, NTOK, D_SZ, D_SZ);

  dim3 ga(T_SZ / 128, B_SZ * NH);
  attn_kernel<<<ga, 256, 0, stream>>>(Qb, Kb, Vtb, xb);  // O overwrites xb

  gemm_bt<1><<<gg, 256, 0, stream>>>(xb, wob, (float*)d_out, NTOK, D_SZ, D_SZ);
}

// Round 4
// 252.544 us; speedup vs baseline: 1.6461x; 1.6461x over previous
//
#include <hip/hip_runtime.h>

typedef float f32x4 __attribute__((ext_vector_type(4)));
typedef float f32x16 __attribute__((ext_vector_type(16)));
typedef short s16x8 __attribute__((ext_vector_type(8)));
typedef unsigned int u32x4 __attribute__((ext_vector_type(4)));

#define B_SZ 4
#define T_SZ 2048
#define D_SZ 1024
#define NH 16
#define HD 64
#define KVB 64

// ---------- helpers ----------
__device__ __forceinline__ unsigned short f2b(float f) {
  unsigned int u = __builtin_bit_cast(unsigned int, f);
  unsigned int r = (u + 0x7fffu + ((u >> 16) & 1u)) >> 16;  // RNE
  return (unsigned short)r;
}

__device__ __forceinline__ void gld_lds16(void* lds, const void* g) {
  __builtin_amdgcn_global_load_lds(
      (const __attribute__((address_space(1))) unsigned int*)g,
      (__attribute__((address_space(3))) unsigned int*)lds, 16, 0, 0);
}

// ---------- fp32 -> bf16 cast ----------
__global__ void cast_kernel(const float* __restrict__ in,
                            unsigned short* __restrict__ out, int n4) {
  int i = blockIdx.x * blockDim.x + threadIdx.x;
  if (i < n4) {
    float4 v = reinterpret_cast<const float4*>(in)[i];
    ushort4 o;
    o.x = f2b(v.x); o.y = f2b(v.y); o.z = f2b(v.z); o.w = f2b(v.w);
    reinterpret_cast<ushort4*>(out)[i] = o;
  }
}

// ---------- GEMM: C[M,N] = A[M,K] * W[N,K]^T  (m97-style 128x128 tile) ----------
// MODE 0: bf16 out row-major. MODE 1: f32 out row-major.
// MODE 2: bf16 out transposed per (b,h): Vt[(b*1024 + col)*2048 + t]
#define BM 128
#define BN 128
#define BKG 32

template <int MODE>
__global__ __launch_bounds__(256, 2) void gemm_bt(
    const unsigned short* __restrict__ A,
    const unsigned short* __restrict__ W,
    void* __restrict__ Cv, int M, int N, int K) {
  __shared__ __align__(16) unsigned short As[BM * BKG];
  __shared__ __align__(16) unsigned short Ws[BN * BKG];
  const int tid = threadIdx.x, wid = tid >> 6, lane = tid & 63;
  const int row0 = blockIdx.x * BM, col0 = blockIdx.y * BN;
  const int wr = (wid >> 1) * 64, wc = (wid & 1) * 64;
  const int fr = lane & 15, kg = (lane >> 4) * 8;
  f32x4 acc[4][4] = {};

  const int srow = lane >> 2;
  const int scol = (lane & 3) * 8;

  for (int k0 = 0; k0 < K; k0 += BKG) {
    __syncthreads();
#pragma unroll
    for (int i = 0; i < 2; ++i) {
      const int c = wid + 4 * i;
      gld_lds16(&As[c * 512], &A[(row0 + c * 16 + srow) * K + k0 + scol]);
      gld_lds16(&Ws[c * 512], &W[(col0 + c * 16 + srow) * K + k0 + scol]);
    }
    __syncthreads();
    s16x8 af[4], bf[4];
#pragma unroll
    for (int m = 0; m < 4; ++m)
      af[m] = *(const s16x8*)&As[(wr + m * 16 + fr) * BKG + kg];
#pragma unroll
    for (int n = 0; n < 4; ++n)
      bf[n] = *(const s16x8*)&Ws[(wc + n * 16 + fr) * BKG + kg];
#pragma unroll
    for (int m = 0; m < 4; ++m)
#pragma unroll
      for (int n = 0; n < 4; ++n)
        acc[m][n] = __builtin_amdgcn_mfma_f32_16x16x32_bf16(af[m], bf[n], acc[m][n], 0, 0, 0);
  }

  const int crow = row0 + wr + ((lane >> 4) << 2);
  const int ccol = col0 + wc + fr;
#pragma unroll
  for (int m = 0; m < 4; ++m)
#pragma unroll
    for (int n = 0; n < 4; ++n) {
      if constexpr (MODE == 2) {
        unsigned short* C = (unsigned short*)Cv;
        ushort4 pk;
        pk.x = f2b(acc[m][n][0]); pk.y = f2b(acc[m][n][1]);
        pk.z = f2b(acc[m][n][2]); pk.w = f2b(acc[m][n][3]);
        const int tok = crow + m * 16;
        const int c = ccol + n * 16;
        *(ushort4*)&C[((tok >> 11) * 1024 + c) * 2048 + (tok & 2047)] = pk;
      } else {
#pragma unroll
        for (int r = 0; r < 4; ++r) {
          const float v = acc[m][n][r];
          const int idx = (crow + m * 16 + r) * N + ccol + n * 16;
          if constexpr (MODE == 0)
            ((unsigned short*)Cv)[idx] = f2b(v);
          else
            ((float*)Cv)[idx] = v;
        }
      }
    }
}

// ---------- flash attention, swapped-operand, LDS-free ----------
// block = 4 waves x 64 q = 256 q; grid (8, 64) = 512 blocks, XCD-swizzled.
// Per wave: 2 q-chunks of 32 (K/V fragments shared as A-operands -> 2x ILP).
// V(t+1) is loop-carried-prefetched at the loop bottom (can't be sunk across
// the back-edge); K loaded at top of iteration (L2-resident, ~200cy).
__global__ __launch_bounds__(256, 2) void attn_kernel(
    const unsigned short* __restrict__ Q,
    const unsigned short* __restrict__ K,
    const unsigned short* __restrict__ Vt,
    unsigned short* __restrict__ O) {
  const int tid = threadIdx.x, wid = tid >> 6, lane = tid & 63;
  const int ql = lane & 31;
  const int hi = lane >> 5;

  // bijective XCD swizzle: 512 blocks = 8 XCD * 64
  const int lin = blockIdx.y * gridDim.x + blockIdx.x;
  const int work = (lin & 7) * 64 + (lin >> 3);
  const int qc = work & 7, bh = work >> 3;
  const int b = bh >> 4, h = bh & 15;
  const int q0 = qc * 256 + wid * 64;
  const int qkbase = b * T_SZ * D_SZ + h * HD;
  const int vtbase = (b * D_SZ + h * HD) * T_SZ;

  // Q B-fragments for both chunks
  s16x8 qf[2][4];
#pragma unroll
  for (int c = 0; c < 2; ++c)
#pragma unroll
    for (int kq = 0; kq < 4; ++kq)
      qf[c][kq] = *(const s16x8*)&Q[qkbase + (q0 + c * 32 + ql) * D_SZ + kq * 16 + hi * 8];

  f32x16 ot[2][2] = {};             // [chunk][dblk]
  float m[2] = {-3e38f, -3e38f}, l[2] = {0.f, 0.f};
  const float cl = 0.125f * 1.44269504089f;  // hd^-0.5 * log2(e)

  // prologue: V fragments for tile 0 (loop-carried prefetch register block)
  s16x8 vf[4][2];
#pragma unroll
  for (int ks = 0; ks < 4; ++ks)
#pragma unroll
    for (int dblk = 0; dblk < 2; ++dblk)
      vf[ks][dblk] = *(const s16x8*)&Vt[vtbase + (dblk * 32 + ql) * T_SZ + ks * 16 + hi * 8];

#pragma unroll 1
  for (int kv0 = 0; kv0 < T_SZ; kv0 += KVB) {
    const int kvn = (kv0 + KVB) & (T_SZ - 1);  // wrap: last prefetch harmless

    // K fragments for this tile, then S^T = K * Q^T (4 independent chains)
    s16x8 kf[8];
#pragma unroll
    for (int blk = 0; blk < 2; ++blk)
#pragma unroll
      for (int kq = 0; kq < 4; ++kq)
        kf[blk * 4 + kq] = *(const s16x8*)&K[qkbase + (kv0 + blk * 32 + ql) * D_SZ + kq * 16 + hi * 8];

    f32x16 st[2][2] = {};             // [chunk][blk]
#pragma unroll
    for (int blk = 0; blk < 2; ++blk)
#pragma unroll
      for (int kq = 0; kq < 4; ++kq) {
        const s16x8 k8 = kf[blk * 4 + kq];
#pragma unroll
        for (int c = 0; c < 2; ++c)
          st[c][blk] = __builtin_amdgcn_mfma_f32_32x32x16_bf16(k8, qf[c][kq], st[c][blk], 0, 0, 0);
      }

    // online softmax per chunk (R2-verified, always-rescale)
#pragma unroll
    for (int c = 0; c < 2; ++c) {
      float mx = st[c][0][0];
#pragma unroll
      for (int blk = 0; blk < 2; ++blk)
#pragma unroll
        for (int r = 0; r < 16; ++r) mx = fmaxf(mx, st[c][blk][r]);
      mx = fmaxf(mx, __shfl_xor(mx, 32, 64));
      const float mn = fmaxf(m[c], mx);
      const float alpha = __builtin_amdgcn_exp2f((m[c] - mn) * cl);
      m[c] = mn;
      float sum = 0.f;
#pragma unroll
      for (int blk = 0; blk < 2; ++blk)
#pragma unroll
        for (int r = 0; r < 16; ++r) {
          const float e = __builtin_amdgcn_exp2f((st[c][blk][r] - mn) * cl);
          st[c][blk][r] = e;
          sum += e;
        }
      sum += __shfl_xor(sum, 32, 64);
      l[c] = l[c] * alpha + sum;
#pragma unroll
      for (int dblk = 0; dblk < 2; ++dblk)
#pragma unroll
        for (int r = 0; r < 16; ++r) ot[c][dblk][r] *= alpha;
    }

    // PV per chunk: P^T fragments via cvt_pk + permlane32_swap, then 8 MFMA
#pragma unroll
    for (int c = 0; c < 2; ++c) {
      s16x8 pf[4];
#pragma unroll
      for (int ks = 0; ks < 4; ++ks) {
        const int blk = ks >> 1, rb = (ks & 1) * 8;
        unsigned int a0, a1, b0, b1;
        asm("v_cvt_pk_bf16_f32 %0, %1, %2" : "=v"(a0) : "v"(st[c][blk][rb + 0]), "v"(st[c][blk][rb + 1]));
        asm("v_cvt_pk_bf16_f32 %0, %1, %2" : "=v"(a1) : "v"(st[c][blk][rb + 2]), "v"(st[c][blk][rb + 3]));
        asm("v_cvt_pk_bf16_f32 %0, %1, %2" : "=v"(b0) : "v"(st[c][blk][rb + 4]), "v"(st[c][blk][rb + 5]));
        asm("v_cvt_pk_bf16_f32 %0, %1, %2" : "=v"(b1) : "v"(st[c][blk][rb + 6]), "v"(st[c][blk][rb + 7]));
        asm("v_permlane32_swap_b32 %0, %1" : "+v"(a0), "+v"(b0));
        asm("v_permlane32_swap_b32 %0, %1" : "+v"(a1), "+v"(b1));
        u32x4 w = {a0, a1, b0, b1};
        pf[ks] = __builtin_bit_cast(s16x8, w);
      }
#pragma unroll
      for (int ks = 0; ks < 4; ++ks)
#pragma unroll
        for (int dblk = 0; dblk < 2; ++dblk)
          ot[c][dblk] = __builtin_amdgcn_mfma_f32_32x32x16_bf16(vf[ks][dblk], pf[ks], ot[c][dblk], 0, 0, 0);
    }

    // loop-carried V prefetch for tile t+1 (consumed next iteration)
#pragma unroll
    for (int ks = 0; ks < 4; ++ks)
#pragma unroll
      for (int dblk = 0; dblk < 2; ++dblk)
        vf[ks][dblk] = *(const s16x8*)&Vt[vtbase + (dblk * 32 + ql) * T_SZ + kvn + ks * 16 + hi * 8];
  }

  // epilogue: normalize (lane-local l) and store bf16 rows of O[q][d]
#pragma unroll
  for (int c = 0; c < 2; ++c) {
    const float inv = 1.f / l[c];
    const int orow = qkbase + (q0 + c * 32 + ql) * D_SZ;
#pragma unroll
    for (int dblk = 0; dblk < 2; ++dblk)
#pragma unroll
      for (int qd = 0; qd < 4; ++qd) {  // d = dblk*32 + qd*8 + hi*4 + (0..3)
        ushort4 pk;
        pk.x = f2b(ot[c][dblk][qd * 4 + 0] * inv);
        pk.y = f2b(ot[c][dblk][qd * 4 + 1] * inv);
        pk.z = f2b(ot[c][dblk][qd * 4 + 2] * inv);
        pk.w = f2b(ot[c][dblk][qd * 4 + 3] * inv);
        *(ushort4*)&O[orow + dblk * 32 + qd * 8 + hi * 4] = pk;
      }
  }
}

// ---------- launch ----------
extern "C" void kernel_launch(void* const* d_in, const int* in_sizes, int n_in,
                              void* d_out, int out_size, void* d_ws, size_t ws_size,
                              hipStream_t stream) {
  const float* x  = (const float*)d_in[0];
  const float* Wq = (const float*)d_in[1];
  const float* Wk = (const float*)d_in[2];
  const float* Wv = (const float*)d_in[3];
  const float* Wo = (const float*)d_in[4];

  const int NTOK = B_SZ * T_SZ;
  const int SZX = NTOK * D_SZ;
  const int SZW = D_SZ * D_SZ;

  unsigned short* ws  = (unsigned short*)d_ws;
  unsigned short* xb  = ws;             // x bf16; reused as attention output O
  unsigned short* wqb = xb + SZX;
  unsigned short* wkb = wqb + SZW;
  unsigned short* wvb = wkb + SZW;
  unsigned short* wob = wvb + SZW;
  unsigned short* Qb  = wob + SZW;
  unsigned short* Kb  = Qb + SZX;
  unsigned short* Vtb = Kb + SZX;       // V transposed per (b,h): [b*1024+c][t]

  cast_kernel<<<SZX / 1024, 256, 0, stream>>>(x, xb, SZX / 4);
  cast_kernel<<<SZW / 1024, 256, 0, stream>>>(Wq, wqb, SZW / 4);
  cast_kernel<<<SZW / 1024, 256, 0, stream>>>(Wk, wkb, SZW / 4);
  cast_kernel<<<SZW / 1024, 256, 0, stream>>>(Wv, wvb, SZW / 4);
  cast_kernel<<<SZW / 1024, 256, 0, stream>>>(Wo, wob, SZW / 4);

  dim3 gg(NTOK / BM, D_SZ / BN);
  gemm_bt<0><<<gg, 256, 0, stream>>>(xb, wqb, Qb, NTOK, D_SZ, D_SZ);
  gemm_bt<0><<<gg, 256, 0, stream>>>(xb, wkb, Kb, NTOK, D_SZ, D_SZ);
  gemm_bt<2><<<gg, 256, 0, stream>>>(xb, wvb, Vtb, NTOK, D_SZ, D_SZ);

  dim3 ga(T_SZ / 256, B_SZ * NH);
  attn_kernel<<<ga, 256, 0, stream>>>(Qb, Kb, Vtb, xb);  // O overwrites xb

  gemm_bt<1><<<gg, 256, 0, stream>>>(xb, wob, (float*)d_out, NTOK, D_SZ, D_SZ);
}